// Round 3
// baseline (633.223 us; speedup 1.0000x reference)
//
#include <hip/hip_runtime.h>
#include <hip/hip_bf16.h>

#define N_NODES 50000
#define N_EDGES 800000
#define IN_N    256
#define D       64

typedef __attribute__((ext_vector_type(8))) short short8;
typedef __attribute__((ext_vector_type(4))) float f32x4;

__device__ __forceinline__ float bf2f(unsigned short h) {
    union { unsigned int u; float f; } x; x.u = ((unsigned int)h) << 16; return x.f;
}
__device__ __forceinline__ unsigned short f2bf(float f) {
    union { float f; unsigned int u; } x; x.f = f;
    unsigned int r = x.u + 0x7fff + ((x.u >> 16) & 1);   // RNE
    return (unsigned short)(r >> 16);
}
__device__ __forceinline__ short8 pack8(f32x4 p0, f32x4 p1) {
    short8 r;
    r[0] = (short)f2bf(p0[0]); r[1] = (short)f2bf(p0[1]);
    r[2] = (short)f2bf(p0[2]); r[3] = (short)f2bf(p0[3]);
    r[4] = (short)f2bf(p1[0]); r[5] = (short)f2bf(p1[1]);
    r[6] = (short)f2bf(p1[2]); r[7] = (short)f2bf(p1[3]);
    return r;
}

__global__ void zero_kernel(f32x4* __restrict__ p, int n4) {
    int i = blockIdx.x * blockDim.x + threadIdx.x;
    int stride = gridDim.x * blockDim.x;
    f32x4 z = {0.f, 0.f, 0.f, 0.f};
    for (; i < n4; i += stride) p[i] = z;
}

// z = nfeats @ W_fc^T  -> bf16.  MFMA 16x16x32: per wave, 16 nodes x 64 outs.
__global__ __launch_bounds__(256) void proj_kernel(
    const float* __restrict__ nf, const float* __restrict__ W_fc,
    unsigned short* __restrict__ z_bf)
{
    __shared__ unsigned short wl[64 * 264];     // row stride 264 shorts: 16B-aligned, ~2-way banks
    for (int i = threadIdx.x; i < 64 * 256; i += 256)
        wl[(i >> 8) * 264 + (i & 255)] = f2bf(W_fc[i]);
    __syncthreads();
    const int lanelo = threadIdx.x & 15, quad = (threadIdx.x >> 4) & 3;
    const int wflat = blockIdx.x * 4 + (threadIdx.x >> 6);
    const int nw = gridDim.x * 4;
    const f32x4 z4 = {0.f, 0.f, 0.f, 0.f};
    for (int g = wflat; g < N_NODES / 16; g += nw) {
        const int n0 = g * 16;
        f32x4 acc[4] = {z4, z4, z4, z4};
        const float* arow = nf + (size_t)(n0 + lanelo) * IN_N;
        #pragma unroll
        for (int h = 0; h < 8; ++h) {
            const float* ap = arow + h * 32 + quad * 8;
            f32x4 p0 = *(const f32x4*)ap;
            f32x4 p1 = *(const f32x4*)(ap + 4);
            short8 a = pack8(p0, p1);
            #pragma unroll
            for (int t = 0; t < 4; ++t) {
                short8 b = *(const short8*)&wl[(t * 16 + lanelo) * 264 + h * 32 + quad * 8];
                acc[t] = __builtin_amdgcn_mfma_f32_16x16x32_bf16(a, b, acc[t], 0, 0, 0);
            }
        }
        #pragma unroll
        for (int t = 0; t < 4; ++t)
            #pragma unroll
            for (int r = 0; r < 4; ++r)
                z_bf[(size_t)(n0 + quad * 4 + r) * D + t * 16 + lanelo] = f2bf(acc[t][r]);
    }
}

// u = z @ W_e[:,0:64]^T + b_e ; v = z @ W_e[:,128:192]^T  -> bf16
__global__ __launch_bounds__(256) void uv_kernel(
    const unsigned short* __restrict__ z_bf, const float* __restrict__ W_e,
    const float* __restrict__ b_e,
    unsigned short* __restrict__ u_bf, unsigned short* __restrict__ v_bf)
{
    __shared__ unsigned short wl[128 * 72];     // rows 0:64 = W1, 64:128 = W3
    for (int i = threadIdx.x; i < 128 * 64; i += 256) {
        int row = i >> 6, col = i & 63;
        float val = (row < 64) ? W_e[(size_t)row * 192 + col]
                               : W_e[(size_t)(row - 64) * 192 + 128 + col];
        wl[row * 72 + col] = f2bf(val);
    }
    __syncthreads();
    const int lanelo = threadIdx.x & 15, quad = (threadIdx.x >> 4) & 3;
    float bias[4];
    #pragma unroll
    for (int t = 0; t < 4; ++t) bias[t] = b_e[t * 16 + lanelo];
    const int wflat = blockIdx.x * 4 + (threadIdx.x >> 6);
    const int nw = gridDim.x * 4;
    const f32x4 z4 = {0.f, 0.f, 0.f, 0.f};
    for (int g = wflat; g < N_NODES / 16; g += nw) {
        const int n0 = g * 16;
        f32x4 acc[8] = {z4, z4, z4, z4, z4, z4, z4, z4};
        #pragma unroll
        for (int h = 0; h < 2; ++h) {
            short8 a = *(const short8*)(z_bf + (size_t)(n0 + lanelo) * D + h * 32 + quad * 8);
            #pragma unroll
            for (int t = 0; t < 8; ++t) {
                short8 b = *(const short8*)&wl[(t * 16 + lanelo) * 72 + h * 32 + quad * 8];
                acc[t] = __builtin_amdgcn_mfma_f32_16x16x32_bf16(a, b, acc[t], 0, 0, 0);
            }
        }
        #pragma unroll
        for (int t = 0; t < 4; ++t)
            #pragma unroll
            for (int r = 0; r < 4; ++r)
                u_bf[(size_t)(n0 + quad * 4 + r) * D + t * 16 + lanelo] = f2bf(acc[t][r] + bias[t]);
        #pragma unroll
        for (int t = 4; t < 8; ++t)
            #pragma unroll
            for (int r = 0; r < 4; ++r)
                v_bf[(size_t)(n0 + quad * 4 + r) * D + (t - 4) * 16 + lanelo] = f2bf(acc[t][r]);
    }
}

// Fused: t = W2@efeat (MFMA, W2 resident in VGPR b-frags); f = leaky(t+u[src]+v[dst]);
// feat_out = f (fp32); a = dot(f,w_c); ex = exp(a); num[dst] += ex*z[src]; s[dst] += ex
__global__ __launch_bounds__(256) void edge_kernel(
    const float* __restrict__ efeats,
    const int* __restrict__ src, const int* __restrict__ dst,
    const float* __restrict__ W_e, const float* __restrict__ w_c,
    const unsigned short* __restrict__ u_bf, const unsigned short* __restrict__ v_bf,
    const unsigned short* __restrict__ z_bf,
    float* __restrict__ s, float* __restrict__ num,
    float* __restrict__ feat_out)
{
    const int lanelo = threadIdx.x & 15, quad = (threadIdx.x >> 4) & 3;
    // W2 = W_e[:, 64:128].  b-frag: B[n=out=lanelo-tile][k=quad*8+j]
    short8 b2[4][2];
    #pragma unroll
    for (int t = 0; t < 4; ++t)
        #pragma unroll
        for (int h = 0; h < 2; ++h)
            #pragma unroll
            for (int j = 0; j < 8; ++j)
                b2[t][h][j] = (short)f2bf(W_e[(size_t)(t * 16 + lanelo) * 192 + 64 + h * 32 + quad * 8 + j]);
    float wcv[4];
    #pragma unroll
    for (int t = 0; t < 4; ++t) wcv[t] = w_c[t * 16 + lanelo];

    const int wflat = blockIdx.x * 4 + (threadIdx.x >> 6);
    const int nw = gridDim.x * 4;
    const f32x4 z4 = {0.f, 0.f, 0.f, 0.f};
    for (int g = wflat; g < N_EDGES / 16; g += nw) {
        const int e0 = g * 16;
        f32x4 acc[4] = {z4, z4, z4, z4};
        const float* ar = efeats + (size_t)(e0 + lanelo) * D;
        #pragma unroll
        for (int h = 0; h < 2; ++h) {
            f32x4 p0 = *(const f32x4*)(ar + h * 32 + quad * 8);
            f32x4 p1 = *(const f32x4*)(ar + h * 32 + quad * 8 + 4);
            short8 a = pack8(p0, p1);
            #pragma unroll
            for (int t = 0; t < 4; ++t)
                acc[t] = __builtin_amdgcn_mfma_f32_16x16x32_bf16(a, b2[t][h], acc[t], 0, 0, 0);
        }
        // this quad's 4 edges: e0 + quad*4 + r  (D row = quad*4+reg)
        int sn[4], dn[4];
        #pragma unroll
        for (int r = 0; r < 4; ++r) {
            sn[r] = src[e0 + quad * 4 + r];
            dn[r] = dst[e0 + quad * 4 + r];
        }
        float part[4];
        #pragma unroll
        for (int r = 0; r < 4; ++r) {
            float p = 0.f;
            #pragma unroll
            for (int t = 0; t < 4; ++t) {
                float f = acc[t][r]
                        + bf2f(u_bf[(size_t)sn[r] * D + t * 16 + lanelo])
                        + bf2f(v_bf[(size_t)dn[r] * D + t * 16 + lanelo]);
                f = f > 0.f ? f : 0.01f * f;
                feat_out[(size_t)(e0 + quad * 4 + r) * D + t * 16 + lanelo] = f;
                p += f * wcv[t];
            }
            part[r] = p;
        }
        #pragma unroll
        for (int st = 1; st < 16; st <<= 1) {
            #pragma unroll
            for (int r = 0; r < 4; ++r) part[r] += __shfl_xor(part[r], st, 64);
        }
        #pragma unroll
        for (int r = 0; r < 4; ++r) {
            float ex = __expf(part[r]);
            #pragma unroll
            for (int t = 0; t < 4; ++t) {
                float zz = bf2f(z_bf[(size_t)sn[r] * D + t * 16 + lanelo]);
                atomicAdd(&num[(size_t)dn[r] * D + t * 16 + lanelo], ex * zz);
            }
            if (lanelo == 0) atomicAdd(&s[dn[r]], ex);
        }
    }
}

__global__ void final_kernel(const float* __restrict__ num,
                             const float* __restrict__ s,
                             float* __restrict__ h)
{
    int i = blockIdx.x * blockDim.x + threadIdx.x;
    if (i < N_NODES * D) {
        float sv = s[i >> 6];
        h[i] = sv > 0.f ? num[i] / sv : 0.f;
    }
}

extern "C" void kernel_launch(void* const* d_in, const int* in_sizes, int n_in,
                              void* d_out, int out_size, void* d_ws, size_t ws_size,
                              hipStream_t stream)
{
    const float* nfeats = (const float*)d_in[0];
    const float* efeats = (const float*)d_in[1];
    const int* src = (const int*)d_in[2];
    const int* dst = (const int*)d_in[3];
    const float* W_fc = (const float*)d_in[4];
    const float* W_e  = (const float*)d_in[5];
    const float* b_e  = (const float*)d_in[6];
    const float* w_c  = (const float*)d_in[7];

    // ws: z_bf | u_bf | v_bf (bf16, 6.4MB each) | s (0.2MB f32) | num (12.8MB f32) = 32.2MB
    unsigned short* z_bf = (unsigned short*)d_ws;
    unsigned short* u_bf = z_bf + (size_t)N_NODES * D;
    unsigned short* v_bf = u_bf + (size_t)N_NODES * D;
    float* s   = (float*)(v_bf + (size_t)N_NODES * D);
    float* num = s + N_NODES;

    float* h_out = (float*)d_out;
    float* f_out = h_out + (size_t)N_NODES * D;

    zero_kernel<<<1024, 256, 0, stream>>>((f32x4*)s, (N_NODES + N_NODES * D) / 4);
    proj_kernel<<<782, 256, 0, stream>>>(nfeats, W_fc, z_bf);
    uv_kernel<<<782, 256, 0, stream>>>(z_bf, W_e, b_e, u_bf, v_bf);
    edge_kernel<<<2048, 256, 0, stream>>>(efeats, src, dst, W_e, w_c, u_bf, v_bf, z_bf, s, num, f_out);
    final_kernel<<<12500, 256, 0, stream>>>(num, s, h_out);
}